// Round 7
// baseline (318.143 us; speedup 1.0000x reference)
//
#include <hip/hip_runtime.h>
#include <math.h>

// Problem constants (B=1)
#define T_SEQ 4096
#define DMODEL 1024
#define NH 16
#define HD 64           // KD = VD = 64
#define NQT (T_SEQ / 64)

typedef _Float16 f16x4 __attribute__((ext_vector_type(4)));
typedef _Float16 f16x8 __attribute__((ext_vector_type(8)));
typedef float f32x4 __attribute__((ext_vector_type(4)));

#define HTD ((size_t)NH * T_SEQ * HD)   // 4,194,304

// ---------------------------------------------------------------------------
// Kernel 0: sin/cos table [t][ sin(32) | cos(32) ]
// ---------------------------------------------------------------------------
__global__ __launch_bounds__(256)
void sincos_table_kernel(float* __restrict__ tab) {
    int idx = blockIdx.x * 256 + threadIdx.x;
    if (idx >= T_SEQ * 32) return;
    int t = idx >> 5, j = idx & 31;
    double p = (double)((float)j / 31.0f);
    float theta = (float)pow(10000.0, p);
    float ang = (float)t / theta;
    double a = (double)ang;
    tab[t * 64 + j]      = (float)sin(a);
    tab[t * 64 + 32 + j] = (float)cos(a);
}

// ---------------------------------------------------------------------------
// Kernel 0.5: cast x, W_in, W_out to f16 (vec8).
// ---------------------------------------------------------------------------
__global__ __launch_bounds__(256)
void cast3_kernel(const float* __restrict__ x, const float* __restrict__ wi,
                  const float* __restrict__ wo, _Float16* __restrict__ x16,
                  _Float16* __restrict__ wi16, _Float16* __restrict__ wo16) {
    size_t gid = (size_t)blockIdx.x * 256 + threadIdx.x;   // 1,048,576 total
    const float* src; _Float16* dst; size_t i;
    if (gid < 524288)       { src = x;  dst = x16;  i = gid; }
    else if (gid < 917504)  { src = wi; dst = wi16; i = gid - 524288; }
    else                    { src = wo; dst = wo16; i = gid - 917504; }
    float4 a = *((const float4*)src + i * 2);
    float4 b = *((const float4*)src + i * 2 + 1);
    f16x8 o = {(_Float16)a.x, (_Float16)a.y, (_Float16)a.z, (_Float16)a.w,
               (_Float16)b.x, (_Float16)b.y, (_Float16)b.z, (_Float16)b.w};
    *((f16x8*)dst + i) = o;
}

// ---------------------------------------------------------------------------
// Kernel 2: RoPE in-place on f16 q16/k16 ([h][t][64]).
// q additionally scaled by 0.125*log2(e): attention runs in the exp2 domain.
// ---------------------------------------------------------------------------
__global__ __launch_bounds__(256)
void rope16_kernel(_Float16* __restrict__ q16, _Float16* __restrict__ k16,
                   const float* __restrict__ tab) {
    int idx = blockIdx.x * 256 + threadIdx.x;   // bits: [z:1][h:4][t:12][j:5]
    int j = idx & 31;
    int t = (idx >> 5) & (T_SEQ - 1);
    int h = (idx >> 17) & (NH - 1);
    int z = idx >> 21;                           // 0 = q, 1 = k
    float s = tab[t * 64 + j];
    float c = tab[t * 64 + 32 + j];
    _Float16* base = (z ? k16 : q16) + ((size_t)h * T_SEQ + t) * HD;
    float a = (float)base[j], b = (float)base[j + 32];
    float lo = b * c + a * s;
    float hi = a * c - b * s;
    if (z == 0) { lo *= 0.18033688f; hi *= 0.18033688f; }  // 0.125*log2(e)
    base[j]      = (_Float16)lo;
    base[j + 32] = (_Float16)hi;
}

// ---------------------------------------------------------------------------
// Kernels 1 & 4: f16 MFMA GEMM  C[M][N] = A[M][K] . B[N][K]^T + bias[N]
// 128x128 tile, BK=64, 4 waves (2x2 of 64x64), mfma_f32_16x16x32_f16.
// EPI=0: f32 out [M][N]. EPI=1: q/k f16 [h][t][64] (roped later), v f16 [h][d][t].
// ---------------------------------------------------------------------------
template<int EPI>
__global__ __launch_bounds__(256)
void gemm16_kernel(const _Float16* __restrict__ A, const _Float16* __restrict__ B,
                   const float* __restrict__ bias, float* __restrict__ out,
                   _Float16* __restrict__ outv, int M, int N, int K, int gx) {
    __shared__ _Float16 Alds[128 * 64];
    __shared__ _Float16 Blds[128 * 64];
    const int tid = threadIdx.x;
    const int w = tid >> 6, lane = tid & 63, lq = lane & 15, lg = lane >> 4;
    const int wr = w >> 1, wc = w & 1;

    // bijective XCD swizzle (gridDim.x % 8 == 0 for both call sites)
    int cpx = (int)gridDim.x >> 3;
    int tileid = (blockIdx.x & 7) * cpx + (blockIdx.x >> 3);
    const int bx = tileid % gx, by = tileid / gx;
    const int row0 = by * 128, col0 = bx * 128;

    const int ra = tid >> 1, ha = tid & 1;
    const _Float16* Ap = A + (size_t)(row0 + ra) * K + ha * 32;
    const _Float16* Bp = B + (size_t)(col0 + ra) * K + ha * 32;
    char* Awr = (char*)Alds + ra * 128;
    char* Bwr = (char*)Blds + ra * 128;
    int wsw[4];
#pragma unroll
    for (int j = 0; j < 4; ++j) wsw[j] = ((ha * 4 + j) ^ (ra & 7)) * 16;

    f32x4 acc[4][4] = {};
    f16x8 sa[4], sb[4];
#pragma unroll
    for (int j = 0; j < 4; ++j) {
        sa[j] = *(const f16x8*)(Ap + j * 8);
        sb[j] = *(const f16x8*)(Bp + j * 8);
    }

    const int nkt = K >> 6;
    for (int kt = 0; kt < nkt; ++kt) {
        __syncthreads();   // previous compute done reading LDS
#pragma unroll
        for (int j = 0; j < 4; ++j) {
            *(f16x8*)(Awr + wsw[j]) = sa[j];
            *(f16x8*)(Bwr + wsw[j]) = sb[j];
        }
        __syncthreads();   // staged
        if (kt + 1 < nkt) {
            int kn = (kt + 1) << 6;
#pragma unroll
            for (int j = 0; j < 4; ++j) {
                sa[j] = *(const f16x8*)(Ap + kn + j * 8);
                sb[j] = *(const f16x8*)(Bp + kn + j * 8);
            }
        }
#pragma unroll
        for (int ks = 0; ks < 2; ++ks) {
            f16x8 af[4], bf[4];
            const int cofs = ((ks * 4 + lg) ^ (lq & 7)) * 16;
#pragma unroll
            for (int i = 0; i < 4; ++i) {
                int rA = wr * 64 + i * 16 + lq;
                int rB = wc * 64 + i * 16 + lq;
                af[i] = *(const f16x8*)((char*)Alds + rA * 128 + cofs);
                bf[i] = *(const f16x8*)((char*)Blds + rB * 128 + cofs);
            }
#pragma unroll
            for (int mi = 0; mi < 4; ++mi)
#pragma unroll
                for (int nj = 0; nj < 4; ++nj)
                    acc[mi][nj] = __builtin_amdgcn_mfma_f32_16x16x32_f16(
                        af[mi], bf[nj], acc[mi][nj], 0, 0, 0);
        }
    }

    // epilogue. D-layout: C[row0+wr*64+mi*16+lg*4+r][col0+wc*64+nj*16+lq]
    if (EPI == 0) {
#pragma unroll
        for (int nj = 0; nj < 4; ++nj) {
            int n = col0 + wc * 64 + nj * 16 + lq;
            float bv = bias[n];
#pragma unroll
            for (int mi = 0; mi < 4; ++mi) {
                int t0 = row0 + wr * 64 + mi * 16 + lg * 4;
#pragma unroll
                for (int r = 0; r < 4; ++r)
                    out[(size_t)(t0 + r) * N + n] = acc[mi][nj][r] + bv;
            }
        }
    } else {
        const int tensor = col0 >> 10;            // 0=q, 1=k, 2=v (no straddle)
        const int m0b = row0 + wr * 64;
        if (tensor == 2) {
            // v: f16 transposed [h][d][t], f16x4 along t
#pragma unroll
            for (int nj = 0; nj < 4; ++nj) {
                int n = col0 + wc * 64 + nj * 16 + lq;
                int nn = n & 1023; int hh = nn >> 6, d = nn & 63;
                float bv = bias[n];
                _Float16* dv = outv + 2 * HTD + (size_t)(hh * 64 + d) * T_SEQ;
#pragma unroll
                for (int mi = 0; mi < 4; ++mi) {
                    int t0 = m0b + mi * 16 + lg * 4;
                    f16x4 val = {(_Float16)(acc[mi][nj][0] + bv),
                                 (_Float16)(acc[mi][nj][1] + bv),
                                 (_Float16)(acc[mi][nj][2] + bv),
                                 (_Float16)(acc[mi][nj][3] + bv)};
                    *(f16x4*)(dv + t0) = val;
                }
            }
        } else {
            // q/k: f16 [h][t][64] (RoPE applied afterwards in-place)
            _Float16* dst = outv + (size_t)tensor * HTD;
#pragma unroll
            for (int nj = 0; nj < 4; ++nj) {
                int n = col0 + wc * 64 + nj * 16 + lq;
                int nn = n & 1023; int hh = nn >> 6, d = nn & 63;
                float bv = bias[n];
                _Float16* dcol = dst + (size_t)hh * T_SEQ * HD + d;
#pragma unroll
                for (int mi = 0; mi < 4; ++mi) {
                    int t0 = m0b + mi * 16 + lg * 4;
#pragma unroll
                    for (int r = 0; r < 4; ++r)
                        dcol[(size_t)(t0 + r) * HD] = (_Float16)(acc[mi][nj][r] + bv);
                }
            }
        }
    }
}

// ---------------------------------------------------------------------------
// Softmax step, defer-max, zero cross-lane in steady state.
// Per-lane ballot (SGPR) gates the rare rescale (which does the 2 shuffles).
// l is a PER-LANE partial (reduced once at kernel end). exp2 domain.
// ---------------------------------------------------------------------------
__device__ __forceinline__ void softmax_step(f32x4 s[4], float& m, float& lp,
                                             f32x4 acc[4], _Float16* Pw,
                                             int lq, int lg) {
    float tmax = s[0][0];
#pragma unroll
    for (int mb = 0; mb < 4; ++mb)
#pragma unroll
        for (int r = 0; r < 4; ++r) tmax = fmaxf(tmax, s[mb][r]);
    if (__ballot(tmax > m + 11.5f)) {        // rare: real max growth
        float g = fmaxf(tmax, __shfl_xor(tmax, 16));
        g = fmaxf(g, __shfl_xor(g, 32));
        float mn  = fmaxf(m, g);
        float scl = exp2f(m - mn);
        m = mn;
        lp *= scl;
#pragma unroll
        for (int mb = 0; mb < 4; ++mb)
#pragma unroll
            for (int r = 0; r < 4; ++r) acc[mb][r] *= scl;
    }
    float tsum = 0.f;
#pragma unroll
    for (int mb = 0; mb < 4; ++mb) {
        float p0 = exp2f(s[mb][0] - m), p1 = exp2f(s[mb][1] - m);
        float p2 = exp2f(s[mb][2] - m), p3 = exp2f(s[mb][3] - m);
        tsum += (p0 + p1) + (p2 + p3);
        f16x4 pk = {(_Float16)p0, (_Float16)p1, (_Float16)p2, (_Float16)p3};
        *(f16x4*)(Pw + (mb * 2 + (lg >> 1)) * 128 + lq * 8 + (lg & 1) * 4) = pk;
    }
    lp += tsum;
}

// ---------------------------------------------------------------------------
// Kernel 3: causal flash attention, f16 MFMA 16x16x32, qBLK=128.
// Each wave owns TWO 16-row q-sets (rows w*16+lq and +64): every K/V LDS
// fragment is read once and feeds two MFMAs (halves LDS traffic). Softmax is
// per-lane with deferred max (no steady-state cross-lane ops); l reduced once
// at the end. Double-buffered K/V; heavy-first grid for natural pairing.
// ---------------------------------------------------------------------------
__global__ __launch_bounds__(256)
void attn_kernel(const _Float16* __restrict__ q16, const _Float16* __restrict__ k16,
                 const _Float16* __restrict__ v16t, _Float16* __restrict__ y16) {
    __shared__ _Float16 Klds[2][64 * 64];  // [key][d], swizzled
    __shared__ _Float16 Vlds[2][64 * 64];  // [d][key], swizzled
    __shared__ _Float16 Plds[8 * 16 * 64]; // per (wave,set) [kg(8)][q(16)][8]

    const int tid  = threadIdx.x;
    const int w    = tid >> 6;
    const int lane = tid & 63;
    const int lq   = lane & 15;
    const int lg   = lane >> 4;

    const int bid = blockIdx.x;                           // 512 blocks
    const int h   = ((bid & 7) << 1) | ((bid >> 3) & 1);  // head -> XCD affinity
    const int qt  = 31 - (bid >> 4);                      // heavy q-tiles first
    const int q0  = qt * 128;

    const _Float16* qh = q16  + (size_t)h * T_SEQ * HD;
    const _Float16* kh = k16  + (size_t)h * T_SEQ * HD;
    const _Float16* vh = v16t + (size_t)h * HD * T_SEQ;

    const int qrow0 = q0 + w * 16 + lq;
    const int qrow1 = qrow0 + 64;

    f16x8 qf0[2], qf1[2];
    qf0[0] = *(const f16x8*)(qh + (size_t)qrow0 * HD + lg * 8);
    qf0[1] = *(const f16x8*)(qh + (size_t)qrow0 * HD + lg * 8 + 32);
    qf1[0] = *(const f16x8*)(qh + (size_t)qrow1 * HD + lg * 8);
    qf1[1] = *(const f16x8*)(qh + (size_t)qrow1 * HD + lg * 8 + 32);

    const int srow = tid >> 4;           // staging row (+16 per it)
    const int scol = (tid & 15) * 4;     // staging f16 col
    const int schk = (tid & 15) >> 1;    // 16B chunk within row
    const int ssub = (tid & 1) * 8;      // byte offset within chunk

    _Float16* Pw0 = Plds + (w * 2 + 0) * 1024;
    _Float16* Pw1 = Plds + (w * 2 + 1) * 1024;

    float m0 = -3e38f, m1 = -3e38f, lp0 = 0.f, lp1 = 0.f;
    f32x4 acc0[4] = {}, acc1[4] = {};

    const int ktmax  = 2 * qt + 1;       // last k-tile (diagonal of set 1)
    const int kt0max = 2 * qt;           // set 0 active while kt <= this

    // prologue: tile 0 -> buffer 0
    f16x4 kreg[4], vreg[4];
#pragma unroll
    for (int it = 0; it < 4; ++it) {
        int row = srow + it * 16;
        kreg[it] = *(const f16x4*)(kh + (size_t)row * HD + scol);
        vreg[it] = *(const f16x4*)(vh + (size_t)row * T_SEQ + scol);
    }
#pragma unroll
    for (int it = 0; it < 4; ++it) {
        int row = srow + it * 16;
        int chunk = schk ^ (row & 7);
        *(f16x4*)((char*)Klds[0] + row * 128 + chunk * 16 + ssub) = kreg[it];
        *(f16x4*)((char*)Vlds[0] + row * 128 + chunk * 16 + ssub) = vreg[it];
    }

    int cur = 0;
    for (int kt = 0; kt <= ktmax; ++kt) {
        __syncthreads();   // buf[cur] staged by all; prev compute done
        if (kt < ktmax) {  // prefetch next tile (hides under compute)
            const int k0n = (kt + 1) * 64;
#pragma unroll
            for (int it = 0; it < 4; ++it) {
                int row = srow + it * 16;
                kreg[it] = *(const f16x4*)(kh + (size_t)(k0n + row) * HD + scol);
                vreg[it] = *(const f16x4*)(vh + (size_t)row * T_SEQ + k0n + scol);
            }
        }
        const bool a0 = (kt <= kt0max);

        // QK^T: each kf read serves both q-sets
        f32x4 s0[4] = {}, s1[4] = {};
        __builtin_amdgcn_s_setprio(1);
#pragma unroll
        for (int mb = 0; mb < 4; ++mb) {
            int row = mb * 16 + lq;
#pragma unroll
            for (int ks = 0; ks < 2; ++ks) {
                f16x8 kf = *(const f16x8*)((char*)Klds[cur] + row * 128 +
                                           (((lg + 4 * ks) ^ (lq & 7)) * 16));
                if (a0) s0[mb] = __builtin_amdgcn_mfma_f32_16x16x32_f16(kf, qf0[ks], s0[mb], 0, 0, 0);
                s1[mb] = __builtin_amdgcn_mfma_f32_16x16x32_f16(kf, qf1[ks], s1[mb], 0, 0, 0);
            }
        }
        __builtin_amdgcn_s_setprio(0);

        // causal masks on each set's diagonal tile
        const int qloc = w * 16 + lq;
        if (kt == kt0max) {
#pragma unroll
            for (int mb = 0; mb < 4; ++mb)
#pragma unroll
                for (int r = 0; r < 4; ++r)
                    if (mb * 16 + lg * 4 + r > qloc) s0[mb][r] = -3e38f;
        }
        if (kt == ktmax) {
#pragma unroll
            for (int mb = 0; mb < 4; ++mb)
#pragma unroll
                for (int r = 0; r < 4; ++r)
                    if (mb * 16 + lg * 4 + r > qloc) s1[mb][r] = -3e38f;
        }

        if (a0) softmax_step(s0, m0, lp0, acc0, Pw0, lq, lg);
        softmax_step(s1, m1, lp1, acc1, Pw1, lq, lg);

        // PV: each vf read serves both q-sets
        f16x8 pf0[2], pf1[2];
        if (a0) {
            pf0[0] = *(const f16x8*)(Pw0 + lg * 128 + lq * 8);
            pf0[1] = *(const f16x8*)(Pw0 + (lg + 4) * 128 + lq * 8);
        }
        pf1[0] = *(const f16x8*)(Pw1 + lg * 128 + lq * 8);
        pf1[1] = *(const f16x8*)(Pw1 + (lg + 4) * 128 + lq * 8);
        __builtin_amdgcn_s_setprio(1);
#pragma unroll
        for (int mb = 0; mb < 4; ++mb) {
            int row = mb * 16 + lq;
#pragma unroll
            for (int ks = 0; ks < 2; ++ks) {
                f16x8 vf = *(const f16x8*)((char*)Vlds[cur] + row * 128 +
                                           (((lg + 4 * ks) ^ (lq & 7)) * 16));
                if (a0) acc0[mb] = __builtin_amdgcn_mfma_f32_16x16x32_f16(vf, pf0[ks], acc0[mb], 0, 0, 0);
                acc1[mb] = __builtin_amdgcn_mfma_f32_16x16x32_f16(vf, pf1[ks], acc1[mb], 0, 0, 0);
            }
        }
        __builtin_amdgcn_s_setprio(0);

        if (kt < ktmax) {  // stage prefetched tile into the other buffer
#pragma unroll
            for (int it = 0; it < 4; ++it) {
                int row = srow + it * 16;
                int chunk = schk ^ (row & 7);
                *(f16x4*)((char*)Klds[cur ^ 1] + row * 128 + chunk * 16 + ssub) = kreg[it];
                *(f16x4*)((char*)Vlds[cur ^ 1] + row * 128 + chunk * 16 + ssub) = vreg[it];
            }
            cur ^= 1;
        }
    }

    // epilogue: reduce per-lane l partials (once), normalize, store f16
    float ls0 = lp0 + __shfl_xor(lp0, 16); ls0 += __shfl_xor(ls0, 32);
    float ls1 = lp1 + __shfl_xor(lp1, 16); ls1 += __shfl_xor(ls1, 32);
    float inv0 = 1.f / ls0, inv1 = 1.f / ls1;
#pragma unroll
    for (int mb = 0; mb < 4; ++mb) {
        f16x4 o0 = {(_Float16)(acc0[mb][0] * inv0), (_Float16)(acc0[mb][1] * inv0),
                    (_Float16)(acc0[mb][2] * inv0), (_Float16)(acc0[mb][3] * inv0)};
        *(f16x4*)(y16 + (size_t)qrow0 * DMODEL + h * HD + mb * 16 + lg * 4) = o0;
        f16x4 o1 = {(_Float16)(acc1[mb][0] * inv1), (_Float16)(acc1[mb][1] * inv1),
                    (_Float16)(acc1[mb][2] * inv1), (_Float16)(acc1[mb][3] * inv1)};
        *(f16x4*)(y16 + (size_t)qrow1 * DMODEL + h * HD + mb * 16 + lg * 4) = o1;
    }
}

// ---------------------------------------------------------------------------
extern "C" void kernel_launch(void* const* d_in, const int* in_sizes, int n_in,
                              void* d_out, int out_size, void* d_ws, size_t ws_size,
                              hipStream_t stream) {
    const float* x     = (const float*)d_in[0];
    const float* W_in  = (const float*)d_in[1];
    const float* b_in  = (const float*)d_in[2];
    const float* W_out = (const float*)d_in[3];
    const float* b_out = (const float*)d_in[4];
    float* out = (float*)d_out;

    float* ws = (float*)d_ws;
    float* tab = ws;                              // [t][64] sin|cos (262144 f32)
    _Float16* fb   = (_Float16*)(ws + (size_t)T_SEQ * 64);
    _Float16* q16  = fb;                          // [h][t][64]
    _Float16* k16  = fb + HTD;                    // [h][t][64]
    _Float16* v16t = fb + 2 * HTD;                // [h][d][t]
    _Float16* x16  = fb + 3 * HTD;                // [t][1024]
    _Float16* y16  = x16;                         // alias: attn writes after proj reads
    _Float16* wi16 = x16 + (size_t)T_SEQ * DMODEL;     // [3072][1024]
    _Float16* wo16 = wi16 + (size_t)3072 * DMODEL;     // [1024][1024]

    // 0) sin/cos table + f16 casts
    sincos_table_kernel<<<(T_SEQ * 32 + 255) / 256, 256, 0, stream>>>(tab);
    cast3_kernel<<<4096, 256, 0, stream>>>(x, W_in, W_out, x16, wi16, wo16);

    // 1) proj GEMM (f16 MFMA): q16, k16 (unroped), v16t
    gemm16_kernel<1><<<768, 256, 0, stream>>>(
        x16, wi16, b_in, nullptr, q16, T_SEQ, 3072, DMODEL, 24);

    // 2) RoPE in-place on q16 (+0.125*log2e scale) and k16
    rope16_kernel<<<(2 * NH * T_SEQ * 32) / 256, 256, 0, stream>>>(q16, k16, tab);

    // 3) causal flash attention -> y16 [t][h*64+d] f16 (qBLK=128, 2 sets/wave)
    attn_kernel<<<512, 256, 0, stream>>>(q16, k16, v16t, y16);

    // 4) out GEMM (f16 MFMA) -> fp32 out
    gemm16_kernel<0><<<256, 256, 0, stream>>>(
        y16, wo16, b_out, out, nullptr, T_SEQ, DMODEL, DMODEL, 8);
}

// Round 9
// 233.266 us; speedup vs baseline: 1.3639x; 1.3639x over previous
//
#include <hip/hip_runtime.h>
#include <math.h>

// Problem constants (B=1)
#define T_SEQ 4096
#define DMODEL 1024
#define NH 16
#define HD 64           // KD = VD = 64
#define NQT (T_SEQ / 64)

typedef _Float16 f16x4 __attribute__((ext_vector_type(4)));
typedef _Float16 f16x8 __attribute__((ext_vector_type(8)));
typedef float f32x4 __attribute__((ext_vector_type(4)));

#define HTD ((size_t)NH * T_SEQ * HD)   // 4,194,304
#define PREC 68                          // floats per partial q-row record

// ---------------------------------------------------------------------------
// Kernel 0: sin/cos table [t][ sin(32) | cos(32) ]
// ---------------------------------------------------------------------------
__global__ __launch_bounds__(256)
void sincos_table_kernel(float* __restrict__ tab) {
    int idx = blockIdx.x * 256 + threadIdx.x;
    if (idx >= T_SEQ * 32) return;
    int t = idx >> 5, j = idx & 31;
    double p = (double)((float)j / 31.0f);
    float theta = (float)pow(10000.0, p);
    float ang = (float)t / theta;
    double a = (double)ang;
    tab[t * 64 + j]      = (float)sin(a);
    tab[t * 64 + 32 + j] = (float)cos(a);
}

// ---------------------------------------------------------------------------
// Kernel 0.5: cast x, W_in, W_out to f16 (vec8).
// ---------------------------------------------------------------------------
__global__ __launch_bounds__(256)
void cast3_kernel(const float* __restrict__ x, const float* __restrict__ wi,
                  const float* __restrict__ wo, _Float16* __restrict__ x16,
                  _Float16* __restrict__ wi16, _Float16* __restrict__ wo16) {
    size_t gid = (size_t)blockIdx.x * 256 + threadIdx.x;   // 1,048,576 total
    const float* src; _Float16* dst; size_t i;
    if (gid < 524288)       { src = x;  dst = x16;  i = gid; }
    else if (gid < 917504)  { src = wi; dst = wi16; i = gid - 524288; }
    else                    { src = wo; dst = wo16; i = gid - 917504; }
    float4 a = *((const float4*)src + i * 2);
    float4 b = *((const float4*)src + i * 2 + 1);
    f16x8 o = {(_Float16)a.x, (_Float16)a.y, (_Float16)a.z, (_Float16)a.w,
               (_Float16)b.x, (_Float16)b.y, (_Float16)b.z, (_Float16)b.w};
    *((f16x8*)dst + i) = o;
}

// ---------------------------------------------------------------------------
// Kernel 2: RoPE in-place on f16 q16/k16 ([h][t][64]).
// q additionally scaled by 0.125*log2(e): attention runs in the exp2 domain.
// ---------------------------------------------------------------------------
__global__ __launch_bounds__(256)
void rope16_kernel(_Float16* __restrict__ q16, _Float16* __restrict__ k16,
                   const float* __restrict__ tab) {
    int idx = blockIdx.x * 256 + threadIdx.x;   // bits: [z:1][h:4][t:12][j:5]
    int j = idx & 31;
    int t = (idx >> 5) & (T_SEQ - 1);
    int h = (idx >> 17) & (NH - 1);
    int z = idx >> 21;                           // 0 = q, 1 = k
    float s = tab[t * 64 + j];
    float c = tab[t * 64 + 32 + j];
    _Float16* base = (z ? k16 : q16) + ((size_t)h * T_SEQ + t) * HD;
    float a = (float)base[j], b = (float)base[j + 32];
    float lo = b * c + a * s;
    float hi = a * c - b * s;
    if (z == 0) { lo *= 0.18033688f; hi *= 0.18033688f; }  // 0.125*log2(e)
    base[j]      = (_Float16)lo;
    base[j + 32] = (_Float16)hi;
}

// ---------------------------------------------------------------------------
// Kernels 1 & 4: f16 MFMA GEMM  C[M][N] = A[M][K] . B[N][K]^T + bias[N]
// 128x128 tile, BK=64, 4 waves (2x2 of 64x64), mfma_f32_16x16x32_f16.
// EPI=0: f32 out [M][N]. EPI=1: q/k f16 [h][t][64] (roped later), v f16 [h][d][t].
// ---------------------------------------------------------------------------
template<int EPI>
__global__ __launch_bounds__(256)
void gemm16_kernel(const _Float16* __restrict__ A, const _Float16* __restrict__ B,
                   const float* __restrict__ bias, float* __restrict__ out,
                   _Float16* __restrict__ outv, int M, int N, int K, int gx) {
    __shared__ _Float16 Alds[128 * 64];
    __shared__ _Float16 Blds[128 * 64];
    const int tid = threadIdx.x;
    const int w = tid >> 6, lane = tid & 63, lq = lane & 15, lg = lane >> 4;
    const int wr = w >> 1, wc = w & 1;

    // bijective XCD swizzle (gridDim.x % 8 == 0 for both call sites)
    int cpx = (int)gridDim.x >> 3;
    int tileid = (blockIdx.x & 7) * cpx + (blockIdx.x >> 3);
    const int bx = tileid % gx, by = tileid / gx;
    const int row0 = by * 128, col0 = bx * 128;

    const int ra = tid >> 1, ha = tid & 1;
    const _Float16* Ap = A + (size_t)(row0 + ra) * K + ha * 32;
    const _Float16* Bp = B + (size_t)(col0 + ra) * K + ha * 32;
    char* Awr = (char*)Alds + ra * 128;
    char* Bwr = (char*)Blds + ra * 128;
    int wsw[4];
#pragma unroll
    for (int j = 0; j < 4; ++j) wsw[j] = ((ha * 4 + j) ^ (ra & 7)) * 16;

    f32x4 acc[4][4] = {};
    f16x8 sa[4], sb[4];
#pragma unroll
    for (int j = 0; j < 4; ++j) {
        sa[j] = *(const f16x8*)(Ap + j * 8);
        sb[j] = *(const f16x8*)(Bp + j * 8);
    }

    const int nkt = K >> 6;
    for (int kt = 0; kt < nkt; ++kt) {
        __syncthreads();   // previous compute done reading LDS
#pragma unroll
        for (int j = 0; j < 4; ++j) {
            *(f16x8*)(Awr + wsw[j]) = sa[j];
            *(f16x8*)(Bwr + wsw[j]) = sb[j];
        }
        __syncthreads();   // staged
        if (kt + 1 < nkt) {
            int kn = (kt + 1) << 6;
#pragma unroll
            for (int j = 0; j < 4; ++j) {
                sa[j] = *(const f16x8*)(Ap + kn + j * 8);
                sb[j] = *(const f16x8*)(Bp + kn + j * 8);
            }
        }
#pragma unroll
        for (int ks = 0; ks < 2; ++ks) {
            f16x8 af[4], bf[4];
            const int cofs = ((ks * 4 + lg) ^ (lq & 7)) * 16;
#pragma unroll
            for (int i = 0; i < 4; ++i) {
                int rA = wr * 64 + i * 16 + lq;
                int rB = wc * 64 + i * 16 + lq;
                af[i] = *(const f16x8*)((char*)Alds + rA * 128 + cofs);
                bf[i] = *(const f16x8*)((char*)Blds + rB * 128 + cofs);
            }
#pragma unroll
            for (int mi = 0; mi < 4; ++mi)
#pragma unroll
                for (int nj = 0; nj < 4; ++nj)
                    acc[mi][nj] = __builtin_amdgcn_mfma_f32_16x16x32_f16(
                        af[mi], bf[nj], acc[mi][nj], 0, 0, 0);
        }
    }

    // epilogue. D-layout: C[row0+wr*64+mi*16+lg*4+r][col0+wc*64+nj*16+lq]
    if (EPI == 0) {
#pragma unroll
        for (int nj = 0; nj < 4; ++nj) {
            int n = col0 + wc * 64 + nj * 16 + lq;
            float bv = bias[n];
#pragma unroll
            for (int mi = 0; mi < 4; ++mi) {
                int t0 = row0 + wr * 64 + mi * 16 + lg * 4;
#pragma unroll
                for (int r = 0; r < 4; ++r)
                    out[(size_t)(t0 + r) * N + n] = acc[mi][nj][r] + bv;
            }
        }
    } else {
        const int tensor = col0 >> 10;            // 0=q, 1=k, 2=v (no straddle)
        const int m0b = row0 + wr * 64;
        if (tensor == 2) {
            // v: f16 transposed [h][d][t], f16x4 along t
#pragma unroll
            for (int nj = 0; nj < 4; ++nj) {
                int n = col0 + wc * 64 + nj * 16 + lq;
                int nn = n & 1023; int hh = nn >> 6, d = nn & 63;
                float bv = bias[n];
                _Float16* dv = outv + 2 * HTD + (size_t)(hh * 64 + d) * T_SEQ;
#pragma unroll
                for (int mi = 0; mi < 4; ++mi) {
                    int t0 = m0b + mi * 16 + lg * 4;
                    f16x4 val = {(_Float16)(acc[mi][nj][0] + bv),
                                 (_Float16)(acc[mi][nj][1] + bv),
                                 (_Float16)(acc[mi][nj][2] + bv),
                                 (_Float16)(acc[mi][nj][3] + bv)};
                    *(f16x4*)(dv + t0) = val;
                }
            }
        } else {
            // q/k: f16 [h][t][64] (RoPE applied afterwards in-place)
            _Float16* dst = outv + (size_t)tensor * HTD;
#pragma unroll
            for (int nj = 0; nj < 4; ++nj) {
                int n = col0 + wc * 64 + nj * 16 + lq;
                int nn = n & 1023; int hh = nn >> 6, d = nn & 63;
                float bv = bias[n];
                _Float16* dcol = dst + (size_t)hh * T_SEQ * HD + d;
#pragma unroll
                for (int mi = 0; mi < 4; ++mi) {
                    int t0 = m0b + mi * 16 + lg * 4;
#pragma unroll
                    for (int r = 0; r < 4; ++r)
                        dcol[(size_t)(t0 + r) * HD] = (_Float16)(acc[mi][nj][r] + bv);
                }
            }
        }
    }
}

// ---------------------------------------------------------------------------
// Softmax step, defer-max, zero cross-lane in steady state (exp2 domain).
// ---------------------------------------------------------------------------
__device__ __forceinline__ void softmax_step(f32x4 s[4], float& m, float& lp,
                                             f32x4 acc[4], _Float16* Pw,
                                             int lq, int lg) {
    float tmax = s[0][0];
#pragma unroll
    for (int mb = 0; mb < 4; ++mb)
#pragma unroll
        for (int r = 0; r < 4; ++r) tmax = fmaxf(tmax, s[mb][r]);
    if (__ballot(tmax > m + 11.5f)) {        // rare: real max growth
        float g = fmaxf(tmax, __shfl_xor(tmax, 16));
        g = fmaxf(g, __shfl_xor(g, 32));
        float mn  = fmaxf(m, g);
        float scl = exp2f(m - mn);
        m = mn;
        lp *= scl;
#pragma unroll
        for (int mb = 0; mb < 4; ++mb)
#pragma unroll
            for (int r = 0; r < 4; ++r) acc[mb][r] *= scl;
    }
    float tsum = 0.f;
#pragma unroll
    for (int mb = 0; mb < 4; ++mb) {
        float p0 = exp2f(s[mb][0] - m), p1 = exp2f(s[mb][1] - m);
        float p2 = exp2f(s[mb][2] - m), p3 = exp2f(s[mb][3] - m);
        tsum += (p0 + p1) + (p2 + p3);
        f16x4 pk = {(_Float16)p0, (_Float16)p1, (_Float16)p2, (_Float16)p3};
        *(f16x4*)(Pw + (mb * 2 + (lg >> 1)) * 128 + lq * 8 + (lg & 1) * 4) = pk;
    }
    lp += tsum;
}

// ---------------------------------------------------------------------------
// Kernel 3a: causal flash attention partial pass, split-K x2.
// Block = (head, 64-row q-tile, k-chunk). Round-6 verified structure:
// 4 waves x 16 q-rows, dbuf K/V LDS, one barrier/iter, per-wave P.
// Writes UNNORMALIZED partial (acc, m, l) per q-row to scratch.
// Grid 2048 -> 4 blocks/CU resident (2x round 6 wave parallelism).
// ---------------------------------------------------------------------------
__global__ __launch_bounds__(256)
void attn_kernel(const _Float16* __restrict__ q16, const _Float16* __restrict__ k16,
                 const _Float16* __restrict__ v16t, float* __restrict__ part) {
    __shared__ _Float16 Klds[2][64 * 64];  // [key][d], swizzled
    __shared__ _Float16 Vlds[2][64 * 64];  // [d][key], swizzled
    __shared__ _Float16 Plds[4 * 16 * 64]; // per-wave [kg(8)][q(16)][8]

    const int tid  = threadIdx.x;
    const int w    = tid >> 6;
    const int lane = tid & 63;
    const int lq   = lane & 15;
    const int lg   = lane >> 4;

    const int bid   = blockIdx.x;                          // 2048 blocks
    const int h     = ((bid & 7) << 1) | ((bid >> 3) & 1); // head -> XCD affinity
    const int rest  = bid >> 4;                            // 0..127
    const int qt    = (NQT - 1) - (rest >> 1);             // heavy q-tiles first
    const int chunk = rest & 1;
    const int nkt   = qt + 1;
    const int half0 = (nkt + 1) >> 1;
    const int c0    = chunk ? half0 : 0;
    const int c1    = chunk ? nkt   : half0;

    const _Float16* qh = q16  + (size_t)h * T_SEQ * HD;
    const _Float16* kh = k16  + (size_t)h * T_SEQ * HD;
    const _Float16* vh = v16t + (size_t)h * HD * T_SEQ;

    const int qrow = qt * 64 + w * 16 + lq;

    f16x8 qf[2];
    qf[0] = *(const f16x8*)(qh + (size_t)qrow * HD + lg * 8);
    qf[1] = *(const f16x8*)(qh + (size_t)qrow * HD + lg * 8 + 32);

    const int srow = tid >> 4;           // staging row (+16 per it)
    const int scol = (tid & 15) * 4;     // staging f16 col
    const int schk = (tid & 15) >> 1;    // 16B chunk within row
    const int ssub = (tid & 1) * 8;      // byte offset within chunk

    _Float16* Pw = Plds + w * 1024;

    float m_r = -3e38f, lp = 0.f;
    f32x4 acc[4] = {};

    if (c0 < c1) {
        // prologue: tile c0 -> buffer 0
        f16x4 kreg[4], vreg[4];
#pragma unroll
        for (int it = 0; it < 4; ++it) {
            int row = srow + it * 16;
            kreg[it] = *(const f16x4*)(kh + (size_t)(c0 * 64 + row) * HD + scol);
            vreg[it] = *(const f16x4*)(vh + (size_t)row * T_SEQ + c0 * 64 + scol);
        }
#pragma unroll
        for (int it = 0; it < 4; ++it) {
            int row = srow + it * 16;
            int chk = schk ^ (row & 7);
            *(f16x4*)((char*)Klds[0] + row * 128 + chk * 16 + ssub) = kreg[it];
            *(f16x4*)((char*)Vlds[0] + row * 128 + chk * 16 + ssub) = vreg[it];
        }

        int cur = 0;
        for (int kt = c0; kt < c1; ++kt) {
            __syncthreads();   // buf[cur] staged by all; prev compute done
            if (kt + 1 < c1) { // prefetch next tile (hides under compute)
                const int k0n = (kt + 1) * 64;
#pragma unroll
                for (int it = 0; it < 4; ++it) {
                    int row = srow + it * 16;
                    kreg[it] = *(const f16x4*)(kh + (size_t)(k0n + row) * HD + scol);
                    vreg[it] = *(const f16x4*)(vh + (size_t)row * T_SEQ + k0n + scol);
                }
            }

            // QK^T: S^T[key][q]
            f32x4 s[4] = {};
            __builtin_amdgcn_s_setprio(1);
#pragma unroll
            for (int mb = 0; mb < 4; ++mb) {
                int row = mb * 16 + lq;
#pragma unroll
                for (int ks = 0; ks < 2; ++ks) {
                    f16x8 kf = *(const f16x8*)((char*)Klds[cur] + row * 128 +
                                               (((lg + 4 * ks) ^ (lq & 7)) * 16));
                    s[mb] = __builtin_amdgcn_mfma_f32_16x16x32_f16(kf, qf[ks], s[mb], 0, 0, 0);
                }
            }
            __builtin_amdgcn_s_setprio(0);
            if (kt == qt) {   // causal mask on diagonal tile
                const int qloc = w * 16 + lq;
#pragma unroll
                for (int mb = 0; mb < 4; ++mb)
#pragma unroll
                    for (int r = 0; r < 4; ++r)
                        if (mb * 16 + lg * 4 + r > qloc) s[mb][r] = -3e38f;
            }

            softmax_step(s, m_r, lp, acc, Pw, lq, lg);

            // PV: O^T[d][q] += V^T[d][key] . P^T[key][q]
            f16x8 pf[2];
            pf[0] = *(const f16x8*)(Pw + lg * 128 + lq * 8);
            pf[1] = *(const f16x8*)(Pw + (lg + 4) * 128 + lq * 8);
            __builtin_amdgcn_s_setprio(1);
#pragma unroll
            for (int mb = 0; mb < 4; ++mb) {
                int row = mb * 16 + lq;
#pragma unroll
                for (int ks = 0; ks < 2; ++ks) {
                    f16x8 vf = *(const f16x8*)((char*)Vlds[cur] + row * 128 +
                                               (((lg + 4 * ks) ^ (lq & 7)) * 16));
                    acc[mb] = __builtin_amdgcn_mfma_f32_16x16x32_f16(vf, pf[ks], acc[mb], 0, 0, 0);
                }
            }
            __builtin_amdgcn_s_setprio(0);

            if (kt + 1 < c1) { // stage prefetched tile into the other buffer
#pragma unroll
                for (int it = 0; it < 4; ++it) {
                    int row = srow + it * 16;
                    int chk = schk ^ (row & 7);
                    *(f16x4*)((char*)Klds[cur ^ 1] + row * 128 + chk * 16 + ssub) = kreg[it];
                    *(f16x4*)((char*)Vlds[cur ^ 1] + row * 128 + chk * 16 + ssub) = vreg[it];
                }
                cur ^= 1;
            }
        }
    }

    // partial epilogue: reduce per-lane l (per-q), store UNNORMALIZED record
    float lsum = lp + __shfl_xor(lp, 16); lsum += __shfl_xor(lsum, 32);
    float* rec = part + ((size_t)((h * NQT + qt) * 2 + chunk) * 64 + w * 16 + lq) * PREC;
#pragma unroll
    for (int mb = 0; mb < 4; ++mb)
        *(float4*)(rec + mb * 16 + lg * 4) =
            make_float4(acc[mb][0], acc[mb][1], acc[mb][2], acc[mb][3]);
    if (lg == 0) { rec[64] = m_r; rec[65] = lsum; }
}

// ---------------------------------------------------------------------------
// Kernel 3b: combine split-K partials -> y16 (f16, [t][h*64+d]).
// 1024 blocks (h, qt); thread = (q-row, 16-d slab). Exact f32 merge.
// ---------------------------------------------------------------------------
__global__ __launch_bounds__(256)
void combine_kernel(const float* __restrict__ part, _Float16* __restrict__ y16) {
    const int bid = blockIdx.x;              // h*64 + qt
    const int h = bid >> 6, qt = bid & 63;
    const int r  = threadIdx.x >> 2;         // 0..63 q-row within tile
    const int dq = (threadIdx.x & 3) * 16;   // 16-d slab

    const float* r0 = part + ((size_t)((h * NQT + qt) * 2 + 0) * 64 + r) * PREC;
    const float* r1 = part + ((size_t)((h * NQT + qt) * 2 + 1) * 64 + r) * PREC;
    float m0 = r0[64], l0 = r0[65];
    float m1 = r1[64], l1 = r1[65];
    float mx = fmaxf(m0, m1);
    float w0 = exp2f(m0 - mx), w1 = exp2f(m1 - mx);
    float inv = 1.f / (l0 * w0 + l1 * w1);
    w0 *= inv; w1 *= inv;

    const int qrow = qt * 64 + r;
    _Float16* yp = y16 + (size_t)qrow * DMODEL + h * HD + dq;
#pragma unroll
    for (int j = 0; j < 2; ++j) {
        float4 a0 = *(const float4*)(r0 + dq + j * 8);
        float4 b0 = *(const float4*)(r0 + dq + j * 8 + 4);
        float4 a1 = *(const float4*)(r1 + dq + j * 8);
        float4 b1 = *(const float4*)(r1 + dq + j * 8 + 4);
        f16x8 o = {(_Float16)(a0.x * w0 + a1.x * w1), (_Float16)(a0.y * w0 + a1.y * w1),
                   (_Float16)(a0.z * w0 + a1.z * w1), (_Float16)(a0.w * w0 + a1.w * w1),
                   (_Float16)(b0.x * w0 + b1.x * w1), (_Float16)(b0.y * w0 + b1.y * w1),
                   (_Float16)(b0.z * w0 + b1.z * w1), (_Float16)(b0.w * w0 + b1.w * w1)};
        *(f16x8*)(yp + j * 8) = o;
    }
}

// ---------------------------------------------------------------------------
extern "C" void kernel_launch(void* const* d_in, const int* in_sizes, int n_in,
                              void* d_out, int out_size, void* d_ws, size_t ws_size,
                              hipStream_t stream) {
    const float* x     = (const float*)d_in[0];
    const float* W_in  = (const float*)d_in[1];
    const float* b_in  = (const float*)d_in[2];
    const float* W_out = (const float*)d_in[3];
    const float* b_out = (const float*)d_in[4];
    float* out = (float*)d_out;

    float* ws = (float*)d_ws;
    float* tab = ws;                              // [t][64] sin|cos (262144 f32)
    _Float16* fb   = (_Float16*)(ws + (size_t)T_SEQ * 64);
    _Float16* q16  = fb;                          // [h][t][64]
    _Float16* k16  = fb + HTD;                    // [h][t][64]
    _Float16* v16t = fb + 2 * HTD;                // [h][d][t]
    _Float16* x16  = fb + 3 * HTD;                // [t][1024]
    _Float16* y16  = x16;                         // alias: combine writes after proj reads
    _Float16* wi16 = x16 + (size_t)T_SEQ * DMODEL;     // [3072][1024]
    _Float16* wo16 = wi16 + (size_t)3072 * DMODEL;     // [1024][1024]
    float* part = (float*)(wo16 + (size_t)DMODEL * DMODEL);  // 2048*64*PREC f32

    // 0) sin/cos table + f16 casts
    sincos_table_kernel<<<(T_SEQ * 32 + 255) / 256, 256, 0, stream>>>(tab);
    cast3_kernel<<<4096, 256, 0, stream>>>(x, W_in, W_out, x16, wi16, wo16);

    // 1) proj GEMM (f16 MFMA): q16, k16 (unroped), v16t
    gemm16_kernel<1><<<768, 256, 0, stream>>>(
        x16, wi16, b_in, nullptr, q16, T_SEQ, 3072, DMODEL, 24);

    // 2) RoPE in-place on q16 (+0.125*log2e scale) and k16
    rope16_kernel<<<(2 * NH * T_SEQ * 32) / 256, 256, 0, stream>>>(q16, k16, tab);

    // 3a) attention partials, split-K x2 (2048 blocks)
    attn_kernel<<<2048, 256, 0, stream>>>(q16, k16, v16t, part);

    // 3b) combine partials -> y16
    combine_kernel<<<NH * NQT, 256, 0, stream>>>(part, y16);

    // 4) out GEMM (f16 MFMA) -> fp32 out
    gemm16_kernel<0><<<256, 256, 0, stream>>>(
        y16, wo16, b_out, out, nullptr, T_SEQ, DMODEL, DMODEL, 8);
}

// Round 12
// 226.739 us; speedup vs baseline: 1.4031x; 1.0288x over previous
//
#include <hip/hip_runtime.h>
#include <math.h>

// Problem constants (B=1)
#define T_SEQ 4096
#define DMODEL 1024
#define NH 16
#define HD 64           // KD = VD = 64
#define NQT (T_SEQ / 64)

typedef _Float16 f16x4 __attribute__((ext_vector_type(4)));
typedef _Float16 f16x8 __attribute__((ext_vector_type(8)));
typedef float f32x4 __attribute__((ext_vector_type(4)));

#define HTD ((size_t)NH * T_SEQ * HD)   // 4,194,304
#define PREC 68                          // floats per partial q-row record

// ---------------------------------------------------------------------------
// Kernel 0: prep = f16 casts (blocks 0..4095) + sin/cos table (blocks 4096+).
// ---------------------------------------------------------------------------
__global__ __launch_bounds__(256)
void prep_kernel(const float* __restrict__ x, const float* __restrict__ wi,
                 const float* __restrict__ wo, _Float16* __restrict__ x16,
                 _Float16* __restrict__ wi16, _Float16* __restrict__ wo16,
                 float* __restrict__ tab) {
    if (blockIdx.x < 4096) {
        size_t gid = (size_t)blockIdx.x * 256 + threadIdx.x;   // 1,048,576 total
        const float* src; _Float16* dst; size_t i;
        if (gid < 524288)       { src = x;  dst = x16;  i = gid; }
        else if (gid < 917504)  { src = wi; dst = wi16; i = gid - 524288; }
        else                    { src = wo; dst = wo16; i = gid - 917504; }
        float4 a = *((const float4*)src + i * 2);
        float4 b = *((const float4*)src + i * 2 + 1);
        f16x8 o = {(_Float16)a.x, (_Float16)a.y, (_Float16)a.z, (_Float16)a.w,
                   (_Float16)b.x, (_Float16)b.y, (_Float16)b.z, (_Float16)b.w};
        *((f16x8*)dst + i) = o;
    } else {
        int idx = (int)(blockIdx.x - 4096) * 256 + threadIdx.x;  // 131072 total
        int t = idx >> 5, j = idx & 31;
        double p = (double)((float)j / 31.0f);
        float theta = (float)pow(10000.0, p);
        float ang = (float)t / theta;
        double a = (double)ang;
        tab[t * 64 + j]      = (float)sin(a);
        tab[t * 64 + 32 + j] = (float)cos(a);
    }
}

// ---------------------------------------------------------------------------
// Kernels 1 & 4: f16 MFMA GEMM  C[M][N] = A[M][K] . B[N][K]^T + bias[N]
// 128x128 tile, BK=64, 4 waves (2x2 of 64x64), mfma_f32_16x16x32_f16.
// EPI=0: f32 out [M][N].
// EPI=1: q/k ROPED f16 [h][t][64] (q scaled by 0.125*log2e), v f16 [h][d][t].
//        RoPE fused: thread holds (d, d+32) as acc[mi][nj] / acc[mi][nj+2].
// ---------------------------------------------------------------------------
template<int EPI>
__global__ __launch_bounds__(256)
void gemm16_kernel(const _Float16* __restrict__ A, const _Float16* __restrict__ B,
                   const float* __restrict__ bias, float* __restrict__ out,
                   _Float16* __restrict__ outv, const float* __restrict__ tab,
                   int M, int N, int K, int gx) {
    __shared__ _Float16 Alds[128 * 64];
    __shared__ _Float16 Blds[128 * 64];
    const int tid = threadIdx.x;
    const int w = tid >> 6, lane = tid & 63, lq = lane & 15, lg = lane >> 4;
    const int wr = w >> 1, wc = w & 1;

    // bijective XCD swizzle (gridDim.x % 8 == 0 for both call sites)
    int cpx = (int)gridDim.x >> 3;
    int tileid = (blockIdx.x & 7) * cpx + (blockIdx.x >> 3);
    const int bx = tileid % gx, by = tileid / gx;
    const int row0 = by * 128, col0 = bx * 128;

    const int ra = tid >> 1, ha = tid & 1;
    const _Float16* Ap = A + (size_t)(row0 + ra) * K + ha * 32;
    const _Float16* Bp = B + (size_t)(col0 + ra) * K + ha * 32;
    char* Awr = (char*)Alds + ra * 128;
    char* Bwr = (char*)Blds + ra * 128;
    int wsw[4];
#pragma unroll
    for (int j = 0; j < 4; ++j) wsw[j] = ((ha * 4 + j) ^ (ra & 7)) * 16;

    f32x4 acc[4][4] = {};
    f16x8 sa[4], sb[4];
#pragma unroll
    for (int j = 0; j < 4; ++j) {
        sa[j] = *(const f16x8*)(Ap + j * 8);
        sb[j] = *(const f16x8*)(Bp + j * 8);
    }

    const int nkt = K >> 6;
    for (int kt = 0; kt < nkt; ++kt) {
        __syncthreads();   // previous compute done reading LDS
#pragma unroll
        for (int j = 0; j < 4; ++j) {
            *(f16x8*)(Awr + wsw[j]) = sa[j];
            *(f16x8*)(Bwr + wsw[j]) = sb[j];
        }
        __syncthreads();   // staged
        if (kt + 1 < nkt) {
            int kn = (kt + 1) << 6;
#pragma unroll
            for (int j = 0; j < 4; ++j) {
                sa[j] = *(const f16x8*)(Ap + kn + j * 8);
                sb[j] = *(const f16x8*)(Bp + kn + j * 8);
            }
        }
#pragma unroll
        for (int ks = 0; ks < 2; ++ks) {
            f16x8 af[4], bf[4];
            const int cofs = ((ks * 4 + lg) ^ (lq & 7)) * 16;
#pragma unroll
            for (int i = 0; i < 4; ++i) {
                int rA = wr * 64 + i * 16 + lq;
                int rB = wc * 64 + i * 16 + lq;
                af[i] = *(const f16x8*)((char*)Alds + rA * 128 + cofs);
                bf[i] = *(const f16x8*)((char*)Blds + rB * 128 + cofs);
            }
#pragma unroll
            for (int mi = 0; mi < 4; ++mi)
#pragma unroll
                for (int nj = 0; nj < 4; ++nj)
                    acc[mi][nj] = __builtin_amdgcn_mfma_f32_16x16x32_f16(
                        af[mi], bf[nj], acc[mi][nj], 0, 0, 0);
        }
    }

    // epilogue. D-layout: C[row0+wr*64+mi*16+lg*4+r][col0+wc*64+nj*16+lq]
    if (EPI == 0) {
#pragma unroll
        for (int nj = 0; nj < 4; ++nj) {
            int n = col0 + wc * 64 + nj * 16 + lq;
            float bv = bias[n];
#pragma unroll
            for (int mi = 0; mi < 4; ++mi) {
                int t0 = row0 + wr * 64 + mi * 16 + lg * 4;
#pragma unroll
                for (int r = 0; r < 4; ++r)
                    out[(size_t)(t0 + r) * N + n] = acc[mi][nj][r] + bv;
            }
        }
    } else {
        const int tensor = col0 >> 10;            // 0=q, 1=k, 2=v (no straddle)
        const int m0b = row0 + wr * 64;
        if (tensor == 2) {
            // v: f16 transposed [h][d][t], f16x4 along t
#pragma unroll
            for (int nj = 0; nj < 4; ++nj) {
                int n = col0 + wc * 64 + nj * 16 + lq;
                int nn = n & 1023; int hh = nn >> 6, d = nn & 63;
                float bv = bias[n];
                _Float16* dv = outv + 2 * HTD + (size_t)(hh * 64 + d) * T_SEQ;
#pragma unroll
                for (int mi = 0; mi < 4; ++mi) {
                    int t0 = m0b + mi * 16 + lg * 4;
                    f16x4 val = {(_Float16)(acc[mi][nj][0] + bv),
                                 (_Float16)(acc[mi][nj][1] + bv),
                                 (_Float16)(acc[mi][nj][2] + bv),
                                 (_Float16)(acc[mi][nj][3] + bv)};
                    *(f16x4*)(dv + t0) = val;
                }
            }
        } else {
            // q/k with FUSED RoPE -> f16 [h][t][64].
            // pairs: (j, j+32) = (acc[mi][nj], acc[mi][nj+2]), j = nj*16+lq.
            const float qs = (tensor == 0) ? 0.18033688f : 1.0f;  // 0.125*log2e
            const int hh = ((col0 & 1023) >> 6) + wc;
            _Float16* dcol = outv + (size_t)tensor * HTD + (size_t)hh * T_SEQ * HD;
            const int nb = col0 + wc * 64 + lq;
            float blo[2] = {bias[nb], bias[nb + 16]};
            float bhi[2] = {bias[nb + 32], bias[nb + 48]};
#pragma unroll
            for (int mi = 0; mi < 4; ++mi) {
#pragma unroll
                for (int r = 0; r < 4; ++r) {
                    int t = m0b + mi * 16 + lg * 4 + r;
                    const float* tb = tab + t * 64;
#pragma unroll
                    for (int nj = 0; nj < 2; ++nj) {
                        int j = nj * 16 + lq;
                        float sn = tb[j], cs = tb[32 + j];
                        float a = acc[mi][nj][r] + blo[nj];       // x[j]
                        float b = acc[mi][nj + 2][r] + bhi[nj];   // x[j+32]
                        dcol[(size_t)t * HD + j]      = (_Float16)((b * cs + a * sn) * qs);
                        dcol[(size_t)t * HD + j + 32] = (_Float16)((a * cs - b * sn) * qs);
                    }
                }
            }
        }
    }
}

// ---------------------------------------------------------------------------
// Softmax step, defer-max, zero cross-lane in steady state (exp2 domain).
// l is accumulated by MFMA (ones-row trick) in the caller, not here.
// ---------------------------------------------------------------------------
__device__ __forceinline__ void softmax_step(f32x4 s[4], float& m,
                                             f32x4 acc[4], f32x4& lacc,
                                             _Float16* Pw, int lq, int lg) {
    float tmax = s[0][0];
#pragma unroll
    for (int mb = 0; mb < 4; ++mb)
#pragma unroll
        for (int r = 0; r < 4; ++r) tmax = fmaxf(tmax, s[mb][r]);
    if (__ballot(tmax > m + 11.5f)) {        // rare: real max growth
        float g = fmaxf(tmax, __shfl_xor(tmax, 16));
        g = fmaxf(g, __shfl_xor(g, 32));
        float mn  = fmaxf(m, g);
        float scl = exp2f(m - mn);
        m = mn;
#pragma unroll
        for (int r = 0; r < 4; ++r) lacc[r] *= scl;
#pragma unroll
        for (int mb = 0; mb < 4; ++mb)
#pragma unroll
            for (int r = 0; r < 4; ++r) acc[mb][r] *= scl;
    }
#pragma unroll
    for (int mb = 0; mb < 4; ++mb) {
        f16x4 pk = {(_Float16)exp2f(s[mb][0] - m), (_Float16)exp2f(s[mb][1] - m),
                    (_Float16)exp2f(s[mb][2] - m), (_Float16)exp2f(s[mb][3] - m)};
        *(f16x4*)(Pw + (mb * 2 + (lg >> 1)) * 128 + lq * 8 + (lg & 1) * 4) = pk;
    }
}

// ---------------------------------------------------------------------------
// Kernel 3a: causal flash attention partial pass, split-K x2.
// Block = (head, 64-row q-tile, k-chunk). 4 waves x 16 q-rows, dbuf K/V LDS,
// one barrier/iter, per-wave P. l summed on the MFMA pipe via a ones-row
// (lacc = mfma(ones, P)) -- removes per-iter VALU adds and end shuffles.
// Writes UNNORMALIZED partial (acc, m, l) per q-row to scratch.
// ---------------------------------------------------------------------------
__global__ __launch_bounds__(256)
void attn_kernel(const _Float16* __restrict__ q16, const _Float16* __restrict__ k16,
                 const _Float16* __restrict__ v16t, float* __restrict__ part) {
    __shared__ _Float16 Klds[2][64 * 64];  // [key][d], swizzled
    __shared__ _Float16 Vlds[2][64 * 64];  // [d][key], swizzled
    __shared__ _Float16 Plds[4 * 16 * 64]; // per-wave [kg(8)][q(16)][8]

    const int tid  = threadIdx.x;
    const int w    = tid >> 6;
    const int lane = tid & 63;
    const int lq   = lane & 15;
    const int lg   = lane >> 4;

    const int bid   = blockIdx.x;                          // 2048 blocks
    const int h     = ((bid & 7) << 1) | ((bid >> 3) & 1); // head -> XCD affinity
    const int rest  = bid >> 4;                            // 0..127
    const int qt    = (NQT - 1) - (rest >> 1);             // heavy q-tiles first
    const int chunk = rest & 1;
    const int nkt   = qt + 1;
    const int half0 = (nkt + 1) >> 1;
    const int c0    = chunk ? half0 : 0;
    const int c1    = chunk ? nkt   : half0;

    const _Float16* qh = q16  + (size_t)h * T_SEQ * HD;
    const _Float16* kh = k16  + (size_t)h * T_SEQ * HD;
    const _Float16* vh = v16t + (size_t)h * HD * T_SEQ;

    const int qrow = qt * 64 + w * 16 + lq;

    f16x8 qf[2];
    qf[0] = *(const f16x8*)(qh + (size_t)qrow * HD + lg * 8);
    qf[1] = *(const f16x8*)(qh + (size_t)qrow * HD + lg * 8 + 32);

    const f16x8 ones = {(_Float16)1, (_Float16)1, (_Float16)1, (_Float16)1,
                        (_Float16)1, (_Float16)1, (_Float16)1, (_Float16)1};

    const int srow = tid >> 4;           // staging row (+16 per it)
    const int scol = (tid & 15) * 4;     // staging f16 col
    const int schk = (tid & 15) >> 1;    // 16B chunk within row
    const int ssub = (tid & 1) * 8;      // byte offset within chunk

    _Float16* Pw = Plds + w * 1024;

    float m_r = -3e38f;
    f32x4 acc[4] = {};
    f32x4 lacc = {};

    if (c0 < c1) {
        // prologue: tile c0 -> buffer 0
        f16x4 kreg[4], vreg[4];
#pragma unroll
        for (int it = 0; it < 4; ++it) {
            int row = srow + it * 16;
            kreg[it] = *(const f16x4*)(kh + (size_t)(c0 * 64 + row) * HD + scol);
            vreg[it] = *(const f16x4*)(vh + (size_t)row * T_SEQ + c0 * 64 + scol);
        }
#pragma unroll
        for (int it = 0; it < 4; ++it) {
            int row = srow + it * 16;
            int chk = schk ^ (row & 7);
            *(f16x4*)((char*)Klds[0] + row * 128 + chk * 16 + ssub) = kreg[it];
            *(f16x4*)((char*)Vlds[0] + row * 128 + chk * 16 + ssub) = vreg[it];
        }

        int cur = 0;
        for (int kt = c0; kt < c1; ++kt) {
            __syncthreads();   // buf[cur] staged by all; prev compute done
            if (kt + 1 < c1) { // prefetch next tile (hides under compute)
                const int k0n = (kt + 1) * 64;
#pragma unroll
                for (int it = 0; it < 4; ++it) {
                    int row = srow + it * 16;
                    kreg[it] = *(const f16x4*)(kh + (size_t)(k0n + row) * HD + scol);
                    vreg[it] = *(const f16x4*)(vh + (size_t)row * T_SEQ + k0n + scol);
                }
            }

            // QK^T: S^T[key][q]
            f32x4 s[4] = {};
            __builtin_amdgcn_s_setprio(1);
#pragma unroll
            for (int mb = 0; mb < 4; ++mb) {
                int row = mb * 16 + lq;
#pragma unroll
                for (int ks = 0; ks < 2; ++ks) {
                    f16x8 kf = *(const f16x8*)((char*)Klds[cur] + row * 128 +
                                               (((lg + 4 * ks) ^ (lq & 7)) * 16));
                    s[mb] = __builtin_amdgcn_mfma_f32_16x16x32_f16(kf, qf[ks], s[mb], 0, 0, 0);
                }
            }
            __builtin_amdgcn_s_setprio(0);
            if (kt == qt) {   // causal mask on diagonal tile
                const int qloc = w * 16 + lq;
#pragma unroll
                for (int mb = 0; mb < 4; ++mb)
#pragma unroll
                    for (int r = 0; r < 4; ++r)
                        if (mb * 16 + lg * 4 + r > qloc) s[mb][r] = -3e38f;
            }

            softmax_step(s, m_r, acc, lacc, Pw, lq, lg);

            // PV: O^T[d][q] += V^T[d][key] . P^T[key][q];  l += ones . P^T
            f16x8 pf[2];
            pf[0] = *(const f16x8*)(Pw + lg * 128 + lq * 8);
            pf[1] = *(const f16x8*)(Pw + (lg + 4) * 128 + lq * 8);
            __builtin_amdgcn_s_setprio(1);
            lacc = __builtin_amdgcn_mfma_f32_16x16x32_f16(ones, pf[0], lacc, 0, 0, 0);
            lacc = __builtin_amdgcn_mfma_f32_16x16x32_f16(ones, pf[1], lacc, 0, 0, 0);
#pragma unroll
            for (int mb = 0; mb < 4; ++mb) {
                int row = mb * 16 + lq;
#pragma unroll
                for (int ks = 0; ks < 2; ++ks) {
                    f16x8 vf = *(const f16x8*)((char*)Vlds[cur] + row * 128 +
                                               (((lg + 4 * ks) ^ (lq & 7)) * 16));
                    acc[mb] = __builtin_amdgcn_mfma_f32_16x16x32_f16(vf, pf[ks], acc[mb], 0, 0, 0);
                }
            }
            __builtin_amdgcn_s_setprio(0);

            if (kt + 1 < c1) { // stage prefetched tile into the other buffer
#pragma unroll
                for (int it = 0; it < 4; ++it) {
                    int row = srow + it * 16;
                    int chk = schk ^ (row & 7);
                    *(f16x4*)((char*)Klds[cur ^ 1] + row * 128 + chk * 16 + ssub) = kreg[it];
                    *(f16x4*)((char*)Vlds[cur ^ 1] + row * 128 + chk * 16 + ssub) = vreg[it];
                }
                cur ^= 1;
            }
        }
    }

    // partial epilogue: store UNNORMALIZED record (lacc rows all equal l)
    float* rec = part + ((size_t)((h * NQT + qt) * 2 + chunk) * 64 + w * 16 + lq) * PREC;
#pragma unroll
    for (int mb = 0; mb < 4; ++mb)
        *(float4*)(rec + mb * 16 + lg * 4) =
            make_float4(acc[mb][0], acc[mb][1], acc[mb][2], acc[mb][3]);
    if (lg == 0) { rec[64] = m_r; rec[65] = lacc[0]; }
}

// ---------------------------------------------------------------------------
// Kernel 3b: combine split-K partials -> y16 (f16, [t][h*64+d]).
// 1024 blocks (h, qt); thread = (q-row, 16-d slab). Exact f32 merge.
// ---------------------------------------------------------------------------
__global__ __launch_bounds__(256)
void combine_kernel(const float* __restrict__ part, _Float16* __restrict__ y16) {
    const int bid = blockIdx.x;              // h*64 + qt
    const int h = bid >> 6, qt = bid & 63;
    const int r  = threadIdx.x >> 2;         // 0..63 q-row within tile
    const int dq = (threadIdx.x & 3) * 16;   // 16-d slab

    const float* r0 = part + ((size_t)((h * NQT + qt) * 2 + 0) * 64 + r) * PREC;
    const float* r1 = part + ((size_t)((h * NQT + qt) * 2 + 1) * 64 + r) * PREC;
    float m0 = r0[64], l0 = r0[65];
    float m1 = r1[64], l1 = r1[65];
    float mx = fmaxf(m0, m1);
    float w0 = exp2f(m0 - mx), w1 = exp2f(m1 - mx);
    float inv = 1.f / (l0 * w0 + l1 * w1);
    w0 *= inv; w1 *= inv;

    const int qrow = qt * 64 + r;
    _Float16* yp = y16 + (size_t)qrow * DMODEL + h * HD + dq;
#pragma unroll
    for (int j = 0; j < 2; ++j) {
        float4 a0 = *(const float4*)(r0 + dq + j * 8);
        float4 b0 = *(const float4*)(r0 + dq + j * 8 + 4);
        float4 a1 = *(const float4*)(r1 + dq + j * 8);
        float4 b1 = *(const float4*)(r1 + dq + j * 8 + 4);
        f16x8 o = {(_Float16)(a0.x * w0 + a1.x * w1), (_Float16)(a0.y * w0 + a1.y * w1),
                   (_Float16)(a0.z * w0 + a1.z * w1), (_Float16)(a0.w * w0 + a1.w * w1),
                   (_Float16)(b0.x * w0 + b1.x * w1), (_Float16)(b0.y * w0 + b1.y * w1),
                   (_Float16)(b0.z * w0 + b1.z * w1), (_Float16)(b0.w * w0 + b1.w * w1)};
        *(f16x8*)(yp + j * 8) = o;
    }
}

// ---------------------------------------------------------------------------
extern "C" void kernel_launch(void* const* d_in, const int* in_sizes, int n_in,
                              void* d_out, int out_size, void* d_ws, size_t ws_size,
                              hipStream_t stream) {
    const float* x     = (const float*)d_in[0];
    const float* W_in  = (const float*)d_in[1];
    const float* b_in  = (const float*)d_in[2];
    const float* W_out = (const float*)d_in[3];
    const float* b_out = (const float*)d_in[4];
    float* out = (float*)d_out;

    float* ws = (float*)d_ws;
    float* tab = ws;                              // [t][64] sin|cos (262144 f32)
    _Float16* fb   = (_Float16*)(ws + (size_t)T_SEQ * 64);
    _Float16* q16  = fb;                          // [h][t][64] (roped, scaled)
    _Float16* k16  = fb + HTD;                    // [h][t][64] (roped)
    _Float16* v16t = fb + 2 * HTD;                // [h][d][t]
    _Float16* x16  = fb + 3 * HTD;                // [t][1024]
    _Float16* y16  = x16;                         // alias: combine writes after proj reads
    _Float16* wi16 = x16 + (size_t)T_SEQ * DMODEL;     // [3072][1024]
    _Float16* wo16 = wi16 + (size_t)3072 * DMODEL;     // [1024][1024]
    float* part = (float*)(wo16 + (size_t)DMODEL * DMODEL);  // 2048*64*PREC f32

    // 0) prep: f16 casts + sin/cos table
    prep_kernel<<<4608, 256, 0, stream>>>(x, W_in, W_out, x16, wi16, wo16, tab);

    // 1) proj GEMM (f16 MFMA): q16/k16 roped in-epilogue, v16t
    gemm16_kernel<1><<<768, 256, 0, stream>>>(
        x16, wi16, b_in, nullptr, q16, tab, T_SEQ, 3072, DMODEL, 24);

    // 2) attention partials, split-K x2 (2048 blocks)
    attn_kernel<<<2048, 256, 0, stream>>>(q16, k16, v16t, part);

    // 3) combine partials -> y16
    combine_kernel<<<NH * NQT, 256, 0, stream>>>(part, y16);

    // 4) out GEMM (f16 MFMA) -> fp32 out
    gemm16_kernel<0><<<256, 256, 0, stream>>>(
        y16, wo16, b_out, out, nullptr, nullptr, T_SEQ, DMODEL, DMODEL, 8);
}